// Round 5
// baseline (53.137 us; speedup 1.0000x reference)
//
#include <hip/hip_runtime.h>
#include <math.h>

typedef float f32x16 __attribute__((ext_vector_type(16)));
typedef float f32x4 __attribute__((ext_vector_type(4)));
typedef __bf16 bf16x8 __attribute__((ext_vector_type(8)));
typedef __bf16 bf16x4 __attribute__((ext_vector_type(4)));

#define N_NODES 2048
#define SCHED_FENCE() __builtin_amdgcn_sched_barrier(0)

__device__ __forceinline__ void gload16(const void* g, void* l) {
    __builtin_amdgcn_global_load_lds(
        (__attribute__((address_space(1))) void*)(uintptr_t)g,
        (__attribute__((address_space(3))) void*)l, 16, 0, 0);
}

__device__ __forceinline__ float elu1(float v) { return v > 0.f ? v : expm1f(v); }

// Stage 1: Wh = X@Ws -> whT_hi/lo (bf16, d-major, XOR-swizzled) + s,t.
// Register-blocked: thread owns (row, 16 d's); per f: 1 broadcast x + 4 b128 Ws reads.
__global__ __launch_bounds__(256) void gat_stage1(
    const float* __restrict__ X, const float* __restrict__ Ws, const float* __restrict__ av,
    __bf16* __restrict__ whT_hi, __bf16* __restrict__ whT_lo,
    float* __restrict__ sv, float* __restrict__ tvv) {
    __shared__ float xls[64][66];   // [row][f]
    __shared__ float wss[64][64];   // [f][d]
    __shared__ float avs[128];
    int tid = threadIdx.x;
    int b = blockIdx.x >> 5;
    int j0 = (blockIdx.x & 31) * 64;
    const float* Xb = X + ((long)(b * N_NODES + j0)) * 64;
#pragma unroll
    for (int k = 0; k < 4; ++k) {
        int i4 = k * 256 + tid;               // 1024 float4s
        float4 v = *reinterpret_cast<const float4*>(Xb + i4 * 4);
        int row = i4 >> 4, c = (i4 & 15) * 4;
        *reinterpret_cast<float2*>(&xls[row][c]) = make_float2(v.x, v.y);
        *reinterpret_cast<float2*>(&xls[row][c + 2]) = make_float2(v.z, v.w);
        *reinterpret_cast<float4*>(&wss[0][0] + i4 * 4) = *reinterpret_cast<const float4*>(Ws + i4 * 4);
    }
    if (tid < 128) avs[tid] = av[tid];
    __syncthreads();
    int row = tid >> 2;            // 0..63 (node j0+row)
    int dblk = (tid & 3) * 16;     // 16-d block
    float acc[16];
#pragma unroll
    for (int k = 0; k < 16; ++k) acc[k] = 0.f;
#pragma unroll 8
    for (int f = 0; f < 64; ++f) {
        float xv = xls[row][f];
        const float4* wr = reinterpret_cast<const float4*>(&wss[f][dblk]);
        float4 w0 = wr[0], w1 = wr[1], w2 = wr[2], w3 = wr[3];
        acc[0]  += xv * w0.x; acc[1]  += xv * w0.y; acc[2]  += xv * w0.z; acc[3]  += xv * w0.w;
        acc[4]  += xv * w1.x; acc[5]  += xv * w1.y; acc[6]  += xv * w1.z; acc[7]  += xv * w1.w;
        acc[8]  += xv * w2.x; acc[9]  += xv * w2.y; acc[10] += xv * w2.z; acc[11] += xv * w2.w;
        acc[12] += xv * w3.x; acc[13] += xv * w3.y; acc[14] += xv * w3.z; acc[15] += xv * w3.w;
    }
    float sp = 0.f, tp = 0.f;
#pragma unroll
    for (int k = 0; k < 16; ++k) {
        int d = dblk + k;
        __bf16 hi = (__bf16)acc[k];
        __bf16 lo = (__bf16)(acc[k] - (float)hi);
        long gidx = ((long)(b * 64 + d) << 11) + j0 + (row ^ ((d & 7) << 3));
        whT_hi[gidx] = hi;
        whT_lo[gidx] = lo;
        sp += acc[k] * avs[d];
        tp += acc[k] * avs[64 + d];
    }
    sp += __shfl_xor(sp, 1, 64); sp += __shfl_xor(sp, 2, 64);
    tp += __shfl_xor(tp, 1, 64); tp += __shfl_xor(tp, 2, 64);
    if ((tid & 3) == 0) {
        sv[b * N_NODES + j0 + row] = sp;
        tvv[b * N_NODES + j0 + row] = tp;
    }
}

// Stage 2: fused masked-softmax attention via MFMA, direct-H.
// 512 threads (8 waves), TI=32 rows, JT=64 chunks, NC=32.
// whT x3 LDS buffers (16KB each), wt x2 (4KB each) = 56KB; ONE barrier/chunk.
__global__ __launch_bounds__(512, 4) void gat_stage2(
    const float* __restrict__ A, const __bf16* __restrict__ whT_hi, const __bf16* __restrict__ whT_lo,
    const float* __restrict__ sv, const float* __restrict__ tvv, float* __restrict__ H) {
    __shared__ __align__(16) char lds[57344];
    // whT bufs [3] x 16KB at 0/16384/32768 (hi +0, lo +8192); wt [2] x 4KB at 49152/53248.
    const int NC = 32;
    int tid = threadIdx.x;
    int nb = gridDim.x;  // 512
    int bid = ((int)blockIdx.x & 7) * (nb >> 3) + ((int)blockIdx.x >> 3);  // XCD x <-> batch b=x
    int b = bid >> 6;
    int it = bid & 63;
    int i0 = it * 32;
    int wid = tid >> 6, lane = tid & 63;

    // phase-A mapping: thread = (1 i-row x 4 j)
    int jq = tid & 15;             // j-quad
    int irow = tid >> 4;           // 0..31
    // staging mapping
    int sd = tid >> 3, sseg = tid & 7;
    const __bf16* srcHi = whT_hi + (((long)(b * 64 + sd)) << 11) + sseg * 8;
    const __bf16* srcLo = whT_lo + (((long)(b * 64 + sd)) << 11) + sseg * 8;
    int waveOff = wid * 1024;

    float s_reg = sv[b * N_NODES + i0 + irow];
    float den = 0.f;
    const float* Abase = A + ((long)(b * N_NODES + i0 + irow)) * N_NODES + jq * 4;
    const float* tb = tvv + b * N_NODES + jq * 4;

    f32x16 acc;
#pragma unroll
    for (int r = 0; r < 16; ++r) acc[r] = 0.f;

    // MFMA constants: wid&1 -> d-half, wid>>1 -> k-slice (16 j each)
    int iAm = lane & 31;
    int dB = (wid & 1) * 32 + (lane & 31);
    int jby = (wid >> 1) * 32 + (lane >> 5) * 16;   // byte offset of 8-elem k-group
    int offA = iAm * 128 + (jby ^ ((iAm & 7) << 4));
    int offB = dB * 128 + (jby ^ ((dB & 7) << 4));
    int wtOff = irow * 128 + ((jq * 8) ^ ((irow & 7) << 4));

    f32x4 a0, a1, t0, t1;
    // prologue: G(0) issued before A(0) loads (G drained by A's counted vmcnt wait)
    { gload16(srcHi, lds + waveOff); gload16(srcLo, lds + waveOff + 8192); }
    SCHED_FENCE();
    a0 = __builtin_nontemporal_load(reinterpret_cast<const f32x4*>(Abase));
    t0 = *reinterpret_cast<const f32x4*>(tb);
    SCHED_FENCE();

#define CHUNK_BODY(c, A_IN, T_IN, A_OUT, T_OUT)                                          \
    {                                                                                     \
        int cn = (c) + 1 < NC ? (c) + 1 : NC - 1;                                         \
        { char* dst = lds + (cn % 3) * 16384 + waveOff;                                   \
          gload16(srcHi + cn * 64, dst); gload16(srcLo + cn * 64, dst + 8192); }          \
        SCHED_FENCE();                                                                    \
        A_OUT = __builtin_nontemporal_load(reinterpret_cast<const f32x4*>(Abase + cn * 64)); \
        T_OUT = *reinterpret_cast<const f32x4*>(tb + cn * 64);                            \
        SCHED_FENCE();                                                                    \
        { char* wt = lds + 49152 + ((c) & 1) * 4096;                                      \
          float e0 = s_reg + T_IN.x, e1 = s_reg + T_IN.y;                                 \
          float e2 = s_reg + T_IN.z, e3 = s_reg + T_IN.w;                                 \
          e0 = fmaxf(e0, 0.2f * e0); e1 = fmaxf(e1, 0.2f * e1);                           \
          e2 = fmaxf(e2, 0.2f * e2); e3 = fmaxf(e3, 0.2f * e3);                           \
          float w0 = A_IN.x * __expf(e0), w1 = A_IN.y * __expf(e1);                       \
          float w2 = A_IN.z * __expf(e2), w3 = A_IN.w * __expf(e3);                       \
          __bf16 q0 = (__bf16)w0, q1 = (__bf16)w1, q2 = (__bf16)w2, q3 = (__bf16)w3;      \
          den += (float)q0 + (float)q1 + (float)q2 + (float)q3;                           \
          bf16x4 wv = {q0, q1, q2, q3};                                                   \
          *reinterpret_cast<bf16x4*>(wt + wtOff) = wv; }                                  \
        asm volatile("s_waitcnt lgkmcnt(0)" ::: "memory");                                \
        __builtin_amdgcn_s_barrier();                                                     \
        SCHED_FENCE();                                                                    \
        { char* whb = lds + ((c) % 3) * 16384;                                            \
          char* wtb = lds + 49152 + ((c) & 1) * 4096;                                     \
          __builtin_amdgcn_s_setprio(1);                                                  \
          bf16x8 af = *reinterpret_cast<const bf16x8*>(wtb + offA);                       \
          bf16x8 bh = *reinterpret_cast<const bf16x8*>(whb + offB);                       \
          bf16x8 bl = *reinterpret_cast<const bf16x8*>(whb + 8192 + offB);                \
          acc = __builtin_amdgcn_mfma_f32_32x32x16_bf16(af, bh, acc, 0, 0, 0);            \
          acc = __builtin_amdgcn_mfma_f32_32x32x16_bf16(af, bl, acc, 0, 0, 0);            \
          __builtin_amdgcn_s_setprio(0); }                                                \
        SCHED_FENCE();                                                                    \
    }

#pragma unroll 1
    for (int c2 = 0; c2 < NC; c2 += 2) {
        CHUNK_BODY(c2, a0, t0, a1, t1)
        CHUNK_BODY(c2 + 1, a1, t1, a0, t0)
    }
#undef CHUNK_BODY

    // drain tail DMA re-issue before reusing staging LDS
    asm volatile("s_waitcnt vmcnt(0)" ::: "memory");
    __syncthreads();
    // scatter acc into per-k-slice regions numl[js][32][64] at js*8192
    {
        float* numl = (float*)(lds + (wid >> 1) * 8192);
        int colD = (wid & 1) * 32 + (lane & 31);
        int rb = 4 * (lane >> 5);
#pragma unroll
        for (int r = 0; r < 16; ++r)
            numl[((r & 3) + 8 * (r >> 2) + rb) * 64 + colD] = acc[r];
    }
    // denominator: reduce over the 16 jq lanes of each i-row
#pragma unroll
    for (int off = 1; off < 16; off <<= 1) den += __shfl_xor(den, off, 64);
    float* den_lds = (float*)(lds + 49152);
    if ((tid & 15) == 0) den_lds[irow] = den;
    __syncthreads();
    // output: thread = (row, 4 cols); sum 4 k-slice partials, divide, elu
    {
        int row = tid >> 4, col4 = (tid & 15) * 4;
        float4 n0 = *reinterpret_cast<float4*>(lds + 0 * 8192 + row * 256 + col4 * 4);
        float4 n1 = *reinterpret_cast<float4*>(lds + 1 * 8192 + row * 256 + col4 * 4);
        float4 n2 = *reinterpret_cast<float4*>(lds + 2 * 8192 + row * 256 + col4 * 4);
        float4 n3 = *reinterpret_cast<float4*>(lds + 3 * 8192 + row * 256 + col4 * 4);
        float dinv = 1.f / den_lds[row];
        f32x4 o;
        o.x = elu1((n0.x + n1.x + n2.x + n3.x) * dinv);
        o.y = elu1((n0.y + n1.y + n2.y + n3.y) * dinv);
        o.z = elu1((n0.z + n1.z + n2.z + n3.z) * dinv);
        o.w = elu1((n0.w + n1.w + n2.w + n3.w) * dinv);
        float* Hrow = H + ((long)(b * N_NODES + i0 + row)) * 64 + col4;
        __builtin_nontemporal_store(o, reinterpret_cast<f32x4*>(Hrow));
    }
}

extern "C" void kernel_launch(void* const* d_in, const int* in_sizes, int n_in,
                              void* d_out, int out_size, void* d_ws, size_t ws_size,
                              hipStream_t stream) {
    const float* A  = (const float*)d_in[0];   // [8,2048,2048]
    const float* X  = (const float*)d_in[1];   // [8,2048,64]
    const float* Ws = (const float*)d_in[2];   // [64,64]
    const float* av = (const float*)d_in[3];   // [128,1]
    float* H = (float*)d_out;                  // [8,2048,64]

    char* ws = (char*)d_ws;
    __bf16* whT_hi = (__bf16*)ws;                           // 2 MiB
    __bf16* whT_lo = (__bf16*)(ws + (1L << 21));            // 2 MiB
    float* sv = (float*)(ws + (1L << 22));                  // 64 KiB
    float* tv = (float*)(ws + (1L << 22) + 65536);          // 64 KiB

    gat_stage1<<<256, 256, 0, stream>>>(X, Ws, av, whT_hi, whT_lo, sv, tv);
    gat_stage2<<<512, 512, 0, stream>>>(A, whT_hi, whT_lo, sv, tv, H);
}

// Round 6
// 40.439 us; speedup vs baseline: 1.3140x; 1.3140x over previous
//
#include <hip/hip_runtime.h>
#include <math.h>

typedef float f32x16 __attribute__((ext_vector_type(16)));
typedef float f32x4 __attribute__((ext_vector_type(4)));
typedef __bf16 bf16x8 __attribute__((ext_vector_type(8)));
typedef __bf16 bf16x4 __attribute__((ext_vector_type(4)));

#define N_NODES 2048
#define SCHED_FENCE() __builtin_amdgcn_sched_barrier(0)

__device__ __forceinline__ void gload16(const void* g, void* l) {
    __builtin_amdgcn_global_load_lds(
        (__attribute__((address_space(1))) void*)(uintptr_t)g,
        (__attribute__((address_space(3))) void*)l, 16, 0, 0);
}

__device__ __forceinline__ float elu1(float v) { return v > 0.f ? v : expm1f(v); }

// Stage 1: Wh = X@Ws -> whT_hi/lo (bf16, d-major, XOR-swizzled) + s,t.
__global__ __launch_bounds__(256) void gat_stage1(
    const float* __restrict__ X, const float* __restrict__ Ws, const float* __restrict__ av,
    __bf16* __restrict__ whT_hi, __bf16* __restrict__ whT_lo,
    float* __restrict__ sv, float* __restrict__ tvv) {
    __shared__ float xls[64][66];   // [row][f]
    __shared__ float wss[64][64];   // [f][d]
    __shared__ float avs[128];
    int tid = threadIdx.x;
    int b = blockIdx.x >> 5;
    int j0 = (blockIdx.x & 31) * 64;
    const float* Xb = X + ((long)(b * N_NODES + j0)) * 64;
#pragma unroll
    for (int k = 0; k < 4; ++k) {
        int i4 = k * 256 + tid;               // 1024 float4s
        float4 v = *reinterpret_cast<const float4*>(Xb + i4 * 4);
        int row = i4 >> 4, c = (i4 & 15) * 4;
        *reinterpret_cast<float2*>(&xls[row][c]) = make_float2(v.x, v.y);
        *reinterpret_cast<float2*>(&xls[row][c + 2]) = make_float2(v.z, v.w);
        *reinterpret_cast<float4*>(&wss[0][0] + i4 * 4) = *reinterpret_cast<const float4*>(Ws + i4 * 4);
    }
    if (tid < 128) avs[tid] = av[tid];
    __syncthreads();
    int row = tid >> 2;            // 0..63 (node j0+row)
    int dblk = (tid & 3) * 16;     // 16-d block
    float acc[16];
#pragma unroll
    for (int k = 0; k < 16; ++k) acc[k] = 0.f;
#pragma unroll 8
    for (int f = 0; f < 64; ++f) {
        float xv = xls[row][f];
        const float4* wr = reinterpret_cast<const float4*>(&wss[f][dblk]);
        float4 w0 = wr[0], w1 = wr[1], w2 = wr[2], w3 = wr[3];
        acc[0]  += xv * w0.x; acc[1]  += xv * w0.y; acc[2]  += xv * w0.z; acc[3]  += xv * w0.w;
        acc[4]  += xv * w1.x; acc[5]  += xv * w1.y; acc[6]  += xv * w1.z; acc[7]  += xv * w1.w;
        acc[8]  += xv * w2.x; acc[9]  += xv * w2.y; acc[10] += xv * w2.z; acc[11] += xv * w2.w;
        acc[12] += xv * w3.x; acc[13] += xv * w3.y; acc[14] += xv * w3.z; acc[15] += xv * w3.w;
    }
    float sp = 0.f, tp = 0.f;
#pragma unroll
    for (int k = 0; k < 16; ++k) {
        int d = dblk + k;
        __bf16 hi = (__bf16)acc[k];
        __bf16 lo = (__bf16)(acc[k] - (float)hi);
        long gidx = ((long)(b * 64 + d) << 11) + j0 + (row ^ ((d & 7) << 3));
        whT_hi[gidx] = hi;
        whT_lo[gidx] = lo;
        sp += acc[k] * avs[d];
        tp += acc[k] * avs[64 + d];
    }
    sp += __shfl_xor(sp, 1, 64); sp += __shfl_xor(sp, 2, 64);
    tp += __shfl_xor(tp, 1, 64); tp += __shfl_xor(tp, 2, 64);
    if ((tid & 3) == 0) {
        sv[b * N_NODES + j0 + row] = sp;
        tvv[b * N_NODES + j0 + row] = tp;
    }
}

// Stage 2: fused masked-softmax attention via MFMA, direct-H.
// 512 threads (8 waves), TI=32 rows, JT=64 chunks, NC=32.
// 2-chunk lookahead: whT x4 LDS buffers (16KB each), A/t in 4-reg rotation;
// wt x2 (4KB). ONE barrier/chunk. LDS = 72KB -> 2 blocks/CU.
__global__ __launch_bounds__(512, 4) void gat_stage2(
    const float* __restrict__ A, const __bf16* __restrict__ whT_hi, const __bf16* __restrict__ whT_lo,
    const float* __restrict__ sv, const float* __restrict__ tvv, float* __restrict__ H) {
    __shared__ __align__(16) char lds[73728];
    // whT bufs [4] x 16KB at 0..65536 (hi +0, lo +8192); wt [2] x 4KB at 65536/69632.
    const int NC = 32;
    int tid = threadIdx.x;
    int nb = gridDim.x;  // 512
    int bid = ((int)blockIdx.x & 7) * (nb >> 3) + ((int)blockIdx.x >> 3);  // XCD x <-> batch b=x
    int b = bid >> 6;
    int it = bid & 63;
    int i0 = it * 32;
    int wid = tid >> 6, lane = tid & 63;

    // phase-A mapping: thread = (1 i-row x 4 j)
    int jq = tid & 15;             // j-quad
    int irow = tid >> 4;           // 0..31
    // staging mapping
    int sd = tid >> 3, sseg = tid & 7;
    const __bf16* srcHi = whT_hi + (((long)(b * 64 + sd)) << 11) + sseg * 8;
    const __bf16* srcLo = whT_lo + (((long)(b * 64 + sd)) << 11) + sseg * 8;
    int waveOff = wid * 1024;

    float s_reg = sv[b * N_NODES + i0 + irow];
    float den = 0.f;
    const float* Abase = A + ((long)(b * N_NODES + i0 + irow)) * N_NODES + jq * 4;
    const float* tb = tvv + b * N_NODES + jq * 4;

    f32x16 acc;
#pragma unroll
    for (int r = 0; r < 16; ++r) acc[r] = 0.f;

    // MFMA constants: wid&1 -> d-half, wid>>1 -> k-slice (16 j each)
    int iAm = lane & 31;
    int dB = (wid & 1) * 32 + (lane & 31);
    int jby = (wid >> 1) * 32 + (lane >> 5) * 16;   // byte offset of 8-elem k-group
    int offA = iAm * 128 + (jby ^ ((iAm & 7) << 4));
    int offB = dB * 128 + (jby ^ ((dB & 7) << 4));
    int wtOff = irow * 128 + ((jq * 8) ^ ((irow & 7) << 4));

    f32x4 a0, a1, a2, a3, t0, t1, t2, t3;
    // prologue: G(0),G(1) issued before A(0),t(0),A(1),t(1)
    { gload16(srcHi, lds + 0 * 16384 + waveOff); gload16(srcLo, lds + 0 * 16384 + waveOff + 8192); }
    { gload16(srcHi + 64, lds + 1 * 16384 + waveOff); gload16(srcLo + 64, lds + 1 * 16384 + waveOff + 8192); }
    SCHED_FENCE();
    a0 = *reinterpret_cast<const f32x4*>(Abase);
    t0 = *reinterpret_cast<const f32x4*>(tb);
    a1 = *reinterpret_cast<const f32x4*>(Abase + 64);
    t1 = *reinterpret_cast<const f32x4*>(tb + 64);
    SCHED_FENCE();

#define CHUNK_BODY(c, A_IN, T_IN, A_OUT, T_OUT)                                          \
    {                                                                                     \
        int cn = (c) + 2 < NC ? (c) + 2 : NC - 1;                                         \
        { char* dst = lds + (cn & 3) * 16384 + waveOff;                                   \
          gload16(srcHi + cn * 64, dst); gload16(srcLo + cn * 64, dst + 8192); }          \
        SCHED_FENCE();                                                                    \
        A_OUT = *reinterpret_cast<const f32x4*>(Abase + cn * 64);                         \
        T_OUT = *reinterpret_cast<const f32x4*>(tb + cn * 64);                            \
        SCHED_FENCE();                                                                    \
        { char* wt = lds + 65536 + ((c) & 1) * 4096;                                      \
          float e0 = s_reg + T_IN.x, e1 = s_reg + T_IN.y;                                 \
          float e2 = s_reg + T_IN.z, e3 = s_reg + T_IN.w;                                 \
          e0 = fmaxf(e0, 0.2f * e0); e1 = fmaxf(e1, 0.2f * e1);                           \
          e2 = fmaxf(e2, 0.2f * e2); e3 = fmaxf(e3, 0.2f * e3);                           \
          float w0 = A_IN.x * __expf(e0), w1 = A_IN.y * __expf(e1);                       \
          float w2 = A_IN.z * __expf(e2), w3 = A_IN.w * __expf(e3);                       \
          __bf16 q0 = (__bf16)w0, q1 = (__bf16)w1, q2 = (__bf16)w2, q3 = (__bf16)w3;      \
          den += (float)q0 + (float)q1 + (float)q2 + (float)q3;                           \
          bf16x4 wv = {q0, q1, q2, q3};                                                   \
          *reinterpret_cast<bf16x4*>(wt + wtOff) = wv; }                                  \
        asm volatile("s_waitcnt lgkmcnt(0)" ::: "memory");                                \
        __builtin_amdgcn_s_barrier();                                                     \
        SCHED_FENCE();                                                                    \
        { char* whb = lds + ((c) & 3) * 16384;                                            \
          char* wtb = lds + 65536 + ((c) & 1) * 4096;                                     \
          __builtin_amdgcn_s_setprio(1);                                                  \
          bf16x8 af = *reinterpret_cast<const bf16x8*>(wtb + offA);                       \
          bf16x8 bh = *reinterpret_cast<const bf16x8*>(whb + offB);                       \
          bf16x8 bl = *reinterpret_cast<const bf16x8*>(whb + 8192 + offB);                \
          acc = __builtin_amdgcn_mfma_f32_32x32x16_bf16(af, bh, acc, 0, 0, 0);            \
          acc = __builtin_amdgcn_mfma_f32_32x32x16_bf16(af, bl, acc, 0, 0, 0);            \
          __builtin_amdgcn_s_setprio(0); }                                                \
        SCHED_FENCE();                                                                    \
    }

#pragma unroll 1
    for (int c4 = 0; c4 < NC; c4 += 4) {
        CHUNK_BODY(c4 + 0, a0, t0, a2, t2)
        CHUNK_BODY(c4 + 1, a1, t1, a3, t3)
        CHUNK_BODY(c4 + 2, a2, t2, a0, t0)
        CHUNK_BODY(c4 + 3, a3, t3, a1, t1)
    }
#undef CHUNK_BODY

    // drain tail DMA re-issue before reusing staging LDS
    asm volatile("s_waitcnt vmcnt(0)" ::: "memory");
    __syncthreads();
    // scatter acc into per-k-slice regions numl[js][32][64] at js*8192
    {
        float* numl = (float*)(lds + (wid >> 1) * 8192);
        int colD = (wid & 1) * 32 + (lane & 31);
        int rb = 4 * (lane >> 5);
#pragma unroll
        for (int r = 0; r < 16; ++r)
            numl[((r & 3) + 8 * (r >> 2) + rb) * 64 + colD] = acc[r];
    }
    // denominator: reduce over the 16 jq lanes of each i-row
#pragma unroll
    for (int off = 1; off < 16; off <<= 1) den += __shfl_xor(den, off, 64);
    float* den_lds = (float*)(lds + 65536);
    if ((tid & 15) == 0) den_lds[irow] = den;
    __syncthreads();
    // output: thread = (row, 4 cols); sum 4 k-slice partials, divide, elu
    {
        int row = tid >> 4, col4 = (tid & 15) * 4;
        float4 n0 = *reinterpret_cast<float4*>(lds + 0 * 8192 + row * 256 + col4 * 4);
        float4 n1 = *reinterpret_cast<float4*>(lds + 1 * 8192 + row * 256 + col4 * 4);
        float4 n2 = *reinterpret_cast<float4*>(lds + 2 * 8192 + row * 256 + col4 * 4);
        float4 n3 = *reinterpret_cast<float4*>(lds + 3 * 8192 + row * 256 + col4 * 4);
        float dinv = 1.f / den_lds[row];
        f32x4 o;
        o.x = elu1((n0.x + n1.x + n2.x + n3.x) * dinv);
        o.y = elu1((n0.y + n1.y + n2.y + n3.y) * dinv);
        o.z = elu1((n0.z + n1.z + n2.z + n3.z) * dinv);
        o.w = elu1((n0.w + n1.w + n2.w + n3.w) * dinv);
        float* Hrow = H + ((long)(b * N_NODES + i0 + row)) * 64 + col4;
        __builtin_nontemporal_store(o, reinterpret_cast<f32x4*>(Hrow));
    }
}

extern "C" void kernel_launch(void* const* d_in, const int* in_sizes, int n_in,
                              void* d_out, int out_size, void* d_ws, size_t ws_size,
                              hipStream_t stream) {
    const float* A  = (const float*)d_in[0];   // [8,2048,2048]
    const float* X  = (const float*)d_in[1];   // [8,2048,64]
    const float* Ws = (const float*)d_in[2];   // [64,64]
    const float* av = (const float*)d_in[3];   // [128,1]
    float* H = (float*)d_out;                  // [8,2048,64]

    char* ws = (char*)d_ws;
    __bf16* whT_hi = (__bf16*)ws;                           // 2 MiB
    __bf16* whT_lo = (__bf16*)(ws + (1L << 21));            // 2 MiB
    float* sv = (float*)(ws + (1L << 22));                  // 64 KiB
    float* tv = (float*)(ws + (1L << 22) + 65536);          // 64 KiB

    gat_stage1<<<256, 256, 0, stream>>>(X, Ws, av, whT_hi, whT_lo, sv, tv);
    gat_stage2<<<512, 512, 0, stream>>>(A, whT_hi, whT_lo, sv, tv, H);
}